// Round 17
// baseline (111.554 us; speedup 1.0000x reference)
//
#include <hip/hip_runtime.h>

#define S_TOT 4096
#define C_DIM 768
#define QKV_LD 2304
#define NH 12
// 1/sqrt(64) * log2(e), folded into Wq so softmax runs in exp2 domain
#define QSCALE 0.18033688011112042f

using f32x4  = __attribute__((ext_vector_type(4))) float;
using bf16x8 = __attribute__((ext_vector_type(8))) __bf16;

#if __has_builtin(__builtin_amdgcn_exp2f)
#define EXP2(x) __builtin_amdgcn_exp2f(x)
#else
#define EXP2(x) exp2f(x)
#endif

__device__ inline unsigned short f2bf_bits(float f) {
  unsigned int u = __float_as_uint(f);
  u = (u + 0x7FFFu + ((u >> 16) & 1u)) >> 16;
  return (unsigned short)u;
}
__device__ inline __bf16 f2bf(float f) {
  unsigned short s = f2bf_bits(f);
  __bf16 b;
  __builtin_memcpy(&b, &s, 2);
  return b;
}

// async global->LDS, 16B per lane; LDS dest = wave-uniform base + lane*16
__device__ __forceinline__ void gl_lds16(const __bf16* g, __bf16* l) {
  __builtin_amdgcn_global_load_lds(
      (__attribute__((address_space(1))) void*)(g),
      (__attribute__((address_space(3))) void*)(l), 16, 0, 0);
}

// One fused f32->bf16 cast for x, Wq(scaled), Wk, Wv, Wo into contiguous ws.
__global__ void cvt_all(const float* __restrict__ x, const float* __restrict__ Wq,
                        const float* __restrict__ Wk, const float* __restrict__ Wv,
                        const float* __restrict__ Wo, __bf16* __restrict__ dst) {
  const int XN = S_TOT * C_DIM;      // 3145728
  const int WN = C_DIM * C_DIM;      // 589824
  int i = (blockIdx.x * blockDim.x + threadIdx.x) * 4;
  if (i >= XN + 4 * WN) return;
  const float* src; float scale = 1.f; int off;
  if (i < XN)               { src = x;  off = i; }
  else if (i < XN + WN)     { src = Wq; off = i - XN; scale = QSCALE; }
  else if (i < XN + 2 * WN) { src = Wk; off = i - XN - WN; }
  else if (i < XN + 3 * WN) { src = Wv; off = i - XN - 2 * WN; }
  else                      { src = Wo; off = i - XN - 3 * WN; }
  float4 v = *reinterpret_cast<const float4*>(src + off);
  ushort4 o;
  o.x = f2bf_bits(v.x * scale); o.y = f2bf_bits(v.y * scale);
  o.z = f2bf_bits(v.z * scale); o.w = f2bf_bits(v.w * scale);
  *reinterpret_cast<ushort4*>(reinterpret_cast<unsigned short*>(dst) + i) = o;
}

// C = A @ B^T, 128x128 tile, BK=64, 4 waves (2x2, each 64x64 = 4x4 frags).
// Counted-vmcnt DOUBLE-BUFFERED K-loop. Barrier A is fully fenced with
// sched_barrier(0) on BOTH sides (R16 post-mortem: without the preceding
// fence, compute(it)'s ds_reads could sink below the next iteration's
// barrier A, racing with stage(it+2) overwriting the same buffer).
// SPLIT_V: n-tiles >=1536 (V projection) written straight from registers
// into Vtp[h][d][tile64*64 + pi(local)] (v9 attention layout).
template<bool OUT_BIAS_F32, bool SPLIT_V>
__global__ __launch_bounds__(256) void gemm128(
    const __bf16* __restrict__ A, const __bf16* __restrict__ B,
    void* __restrict__ Cv, const float* __restrict__ bias,
    __bf16* __restrict__ VtOut, int K, int ldc) {
  __shared__ __bf16 As[2][128][64];
  __shared__ __bf16 Bs[2][128][64];
  const int t = threadIdx.x, lane = t & 63, wv = t >> 6;
  const int wr = wv >> 1, wc = wv & 1;
  const int lhi = lane >> 4, llo = lane & 15;
  const int m0 = blockIdx.y * 128, n0 = blockIdx.x * 128;

  f32x4 acc[4][4];
  #pragma unroll
  for (int a = 0; a < 4; ++a)
    #pragma unroll
    for (int b = 0; b < 4; ++b) acc[a][b] = (f32x4){0.f, 0.f, 0.f, 0.f};

  auto stage = [&](int kt, int buf) {
    #pragma unroll
    for (int n = 0; n < 4; ++n) {
      const int ci = n * 256 + wv * 64 + lane;   // 16B-chunk id 0..1023
      const int r = ci >> 3;                     // tile row 0..127
      const int cc = (ci & 7) ^ (r & 7);         // inverse-swizzled src chunk
      gl_lds16(A + (size_t)(m0 + r) * K + kt + cc * 8, &As[buf][0][0] + ci * 8);
      gl_lds16(B + (size_t)(n0 + r) * K + kt + cc * 8, &Bs[buf][0][0] + ci * 8);
    }
  };

  const int nk = K >> 6;
  stage(0, 0);
  for (int it = 0; it < nk; ++it) {
    // barrier A: all waves done with compute(it-1). FENCED BOTH SIDES.
    __builtin_amdgcn_sched_barrier(0);
    __builtin_amdgcn_s_barrier();
    __builtin_amdgcn_sched_barrier(0);
    if (it + 1 < nk) {
      stage((it + 1) * 64, (it + 1) & 1);    // overwrites buf read at it-1 (safe)
      asm volatile("s_waitcnt vmcnt(8)" ::: "memory");   // my tile-it loads done
    } else {
      asm volatile("s_waitcnt vmcnt(0)" ::: "memory");
    }
    __builtin_amdgcn_sched_barrier(0);
    __builtin_amdgcn_s_barrier();            // B: everyone's tile-it data in LDS
    __builtin_amdgcn_sched_barrier(0);
    const __bf16* Ab = &As[it & 1][0][0];
    const __bf16* Bb = &Bs[it & 1][0][0];
    #pragma unroll
    for (int kk = 0; kk < 2; ++kk) {
      bf16x8 af[4], bfr[4];
      #pragma unroll
      for (int mi = 0; mi < 4; ++mi) {
        const int row = wr * 64 + mi * 16 + llo;
        af[mi] = *reinterpret_cast<const bf16x8*>(
            Ab + row * 64 + (((kk << 2) | lhi) ^ (llo & 7)) * 8);
      }
      #pragma unroll
      for (int ni = 0; ni < 4; ++ni) {
        const int row = wc * 64 + ni * 16 + llo;
        bfr[ni] = *reinterpret_cast<const bf16x8*>(
            Bb + row * 64 + (((kk << 2) | lhi) ^ (llo & 7)) * 8);
      }
      #pragma unroll
      for (int mi = 0; mi < 4; ++mi)
        #pragma unroll
        for (int ni = 0; ni < 4; ++ni)
          acc[mi][ni] = __builtin_amdgcn_mfma_f32_16x16x32_bf16(af[mi], bfr[ni], acc[mi][ni], 0, 0, 0);
    }
  }

  if (SPLIT_V && n0 >= 1536) {
    // V projection: write registers straight to pi-permuted Vtp (v9 layout).
    const int head = (n0 - 1536 + wc * 64) >> 6;       // uniform per wave
    const int tile64 = (m0 >> 6) + wr;
    #pragma unroll
    for (int mi = 0; mi < 4; ++mi) {
      const int p = (mi >> 1) * 32 + lhi * 8 + (mi & 1) * 4;
      #pragma unroll
      for (int ni = 0; ni < 4; ++ni) {
        const int d = ni * 16 + llo;
        ushort4 o;
        o.x = f2bf_bits(acc[mi][ni][0]); o.y = f2bf_bits(acc[mi][ni][1]);
        o.z = f2bf_bits(acc[mi][ni][2]); o.w = f2bf_bits(acc[mi][ni][3]);
        uint2 u; __builtin_memcpy(&u, &o, 8);
        *reinterpret_cast<uint2*>(VtOut + ((size_t)head * 64 + d) * S_TOT + tile64 * 64 + p) = u;
      }
    }
    return;
  }

  #pragma unroll
  for (int mi = 0; mi < 4; ++mi)
    #pragma unroll
    for (int ni = 0; ni < 4; ++ni)
      #pragma unroll
      for (int i = 0; i < 4; ++i) {
        const int row = m0 + wr * 64 + mi * 16 + lhi * 4 + i;
        const int col = n0 + wc * 64 + ni * 16 + llo;
        if constexpr (OUT_BIAS_F32) {
          reinterpret_cast<float*>(Cv)[(size_t)row * ldc + col] = acc[mi][ni][i] + bias[col];
        } else {
          reinterpret_cast<__bf16*>(Cv)[(size_t)row * ldc + col] = f2bf(acc[mi][ni][i]);
        }
      }
}

// v9 block decode: 1152 blocks, heavy-first weight classes. Views 4-7
// (qb64 32..63) are split 2-ways over kv (additive O/l partials, merged by
// merge9); views 0-3 unsplit. Bijective over the 1152 units.
__device__ __forceinline__ void decode9(int j, int& qb64, int& h, int& half, bool& split) {
  if (j < 192)      { split = true;  half = j & 1;  qb64 = 56 + ((j >> 1) & 7); h = j >> 4; }
  else if (j < 288) { int k = j - 192; split = false; half = 0; qb64 = 24 + (k & 7); h = k >> 3; }
  else if (j < 480) { int k = j - 288; split = true;  half = k & 1; qb64 = 48 + ((k >> 1) & 7); h = k >> 4; }
  else if (j < 672) { int k = j - 480; split = true;  half = k & 1; qb64 = 40 + ((k >> 1) & 7); h = k >> 4; }
  else if (j < 768) { int k = j - 672; split = false; half = 0; qb64 = 16 + (k & 7); h = k >> 3; }
  else if (j < 960) { int k = j - 768; split = true;  half = k & 1; qb64 = 32 + ((k >> 1) & 7); h = k >> 4; }
  else              { int k = j - 960; split = false; half = 0; qb64 = k & 15; h = k >> 4; }
}

// Flash attention v9 (best measured: 57.0 us attn; clean replay in R10):
// 4 waves / 64 q-rows per block; kv-split per decode9. K AND V staged in
// triple-buffered LDS, depth-2 counted-vmcnt pipeline (steady vmcnt(4)),
// raw s_barrier with asm-fence + sched_barrier discipline. Max-free exp2
// softmax (O, l additive over kv).
__global__ __launch_bounds__(256) void attn_fused9(
    const __bf16* __restrict__ QKV, const __bf16* __restrict__ Vtp,
    __bf16* __restrict__ att, float* __restrict__ Opart,
    float* __restrict__ lpart) {
  __shared__ __bf16 Ks[3][64][64];
  __shared__ __bf16 Vs[3][64][64];
  const int t = threadIdx.x, lane = t & 63, wv = t >> 6;
  const int llo = lane & 15, hi = lane >> 4;
  const int sw = llo & 7;
  int qb64, h, half; bool split;
  decode9((int)blockIdx.x, qb64, h, half, split);
  const int vq = qb64 >> 3;
  const int kv_end = (vq <= 1) ? 1024 : (vq + 1) * 512;
  const int n_tiles = split ? (kv_end >> 7) : (kv_end >> 6);   // 16..32
  const int kstart = split ? half * (kv_end >> 1) : 0;
  const int q0 = qb64 * 64;
  const int myq = q0 + wv * 16 + llo;

  bf16x8 qf[2];
  {
    const __bf16* qrow = QKV + (size_t)myq * QKV_LD + h * 64;
    qf[0] = *reinterpret_cast<const bf16x8*>(qrow + hi * 8);
    qf[1] = *reinterpret_cast<const bf16x8*>(qrow + 32 + hi * 8);
  }
  // Drain q loads so the only in-loop vmem stream is the counted gl_lds set.
  asm volatile("s_waitcnt vmcnt(0)" ::: "memory");

  f32x4 Oa[4];
  #pragma unroll
  for (int dt = 0; dt < 4; ++dt) Oa[dt] = (f32x4){0.f, 0.f, 0.f, 0.f};
  float l = 0.f;   // per-lane partial (own 16 keys per tile); reduced at end

  // Per-thread staging pointers: two 16B chunks each of K and V per tile,
  // advanced by fixed strides (stages are issued in tile order).
  const int ci0 = (wv * 2 + 0) * 64 + lane, r0 = ci0 >> 3, c0 = (ci0 & 7) ^ (r0 & 7);
  const int ci1 = (wv * 2 + 1) * 64 + lane, r1 = ci1 >> 3, c1 = (ci1 & 7) ^ (r1 & 7);
  const __bf16* kp0 = QKV + (size_t)(kstart + r0) * QKV_LD + C_DIM + h * 64 + c0 * 8;
  const __bf16* kp1 = QKV + (size_t)(kstart + r1) * QKV_LD + C_DIM + h * 64 + c1 * 8;
  const __bf16* vp0 = Vtp + ((size_t)h * 64 + r0) * S_TOT + kstart + c0 * 8;
  const __bf16* vp1 = Vtp + ((size_t)h * 64 + r1) * S_TOT + kstart + c1 * 8;
  __bf16* const kd0 = &Ks[0][0][0] + (wv * 2 + 0) * 512;   // wave-uniform base
  __bf16* const kd1 = &Ks[0][0][0] + (wv * 2 + 1) * 512;
  __bf16* const vd0 = &Vs[0][0][0] + (wv * 2 + 0) * 512;
  __bf16* const vd1 = &Vs[0][0][0] + (wv * 2 + 1) * 512;

  auto stage = [&](int buf) {
    const size_t bo = (size_t)buf * 4096;
    gl_lds16(kp0, kd0 + bo);
    gl_lds16(vp0, vd0 + bo);
    gl_lds16(kp1, kd1 + bo);
    gl_lds16(vp1, vd1 + bo);
    kp0 += (size_t)64 * QKV_LD; kp1 += (size_t)64 * QKV_LD;
    vp0 += 64; vp1 += 64;
  };

  stage(0);
  stage(1);
  int cur = 0;
  for (int tt = 0; tt < n_tiles; ++tt) {
    // retire tile tt's 4 loads; keep tile tt+1's 4 in flight (when present)
    if (tt + 1 < n_tiles) {
      asm volatile("s_waitcnt vmcnt(4)" ::: "memory");
    } else {
      asm volatile("s_waitcnt vmcnt(0)" ::: "memory");
    }
    __builtin_amdgcn_sched_barrier(0);
    __builtin_amdgcn_s_barrier();
    __builtin_amdgcn_sched_barrier(0);
    if (tt + 2 < n_tiles) {
      const int nxt = (cur + 2 >= 3) ? cur - 1 : cur + 2;
      stage(nxt);
    }
    const __bf16* Kb = &Ks[cur][0][0];
    const __bf16* Vb = &Vs[cur][0][0];

    // ---- QK^T (swapped): 8 mfma, operands from swizzled LDS
    f32x4 sc[4];
    #pragma unroll
    for (int nt = 0; nt < 4; ++nt) sc[nt] = (f32x4){0.f, 0.f, 0.f, 0.f};
    #pragma unroll
    for (int nt = 0; nt < 4; ++nt) {
      const __bf16* kr = Kb + (nt * 16 + llo) * 64;
      bf16x8 kf0 = *reinterpret_cast<const bf16x8*>(kr + ((hi ^ sw) * 8));
      bf16x8 kf1 = *reinterpret_cast<const bf16x8*>(kr + (((4 + hi) ^ sw) * 8));
      sc[nt] = __builtin_amdgcn_mfma_f32_16x16x32_bf16(kf0, qf[0], sc[nt], 0, 0, 0);
      sc[nt] = __builtin_amdgcn_mfma_f32_16x16x32_bf16(kf1, qf[1], sc[nt], 0, 0, 0);
    }

    // ---- P = exp2(S) directly (no max; scores' std ~1.44, f32 catastrophe
    // needs S > 115), per-lane l partial
    float pp[4][4];
    #pragma unroll
    for (int nt = 0; nt < 4; ++nt)
      #pragma unroll
      for (int i = 0; i < 4; ++i) pp[nt][i] = EXP2(sc[nt][i]);
    float t0 = (pp[0][0] + pp[0][1]) + (pp[0][2] + pp[0][3]);
    float t1 = (pp[1][0] + pp[1][1]) + (pp[1][2] + pp[1][3]);
    float t2 = (pp[2][0] + pp[2][1]) + (pp[2][2] + pp[2][3]);
    float t3 = (pp[3][0] + pp[3][1]) + (pp[3][2] + pp[3][3]);
    l += (t0 + t1) + (t2 + t3);

    bf16x8 pf[2];
    #pragma unroll
    for (int mm = 0; mm < 2; ++mm)
      #pragma unroll
      for (int jj = 0; jj < 8; ++jj)
        pf[mm][jj] = (__bf16)pp[2 * mm + (jj >> 2)][jj & 3];

    // ---- PV (swapped, O^T): 8 mfma
    #pragma unroll
    for (int dt = 0; dt < 4; ++dt) {
      const __bf16* vr = Vb + (dt * 16 + llo) * 64;
      #pragma unroll
      for (int mm = 0; mm < 2; ++mm) {
        bf16x8 va = *reinterpret_cast<const bf16x8*>(vr + (((mm * 4 + hi) ^ sw) * 8));
        Oa[dt] = __builtin_amdgcn_mfma_f32_16x16x32_bf16(va, pf[mm], Oa[dt], 0, 0, 0);
      }
    }
    cur = (cur + 1 == 3) ? 0 : cur + 1;
  }

  // ---- epilogue
  l += __shfl_xor(l, 16);
  l += __shfl_xor(l, 32);
  if (!split) {
    const float inv = 1.f / l;
    #pragma unroll
    for (int dt = 0; dt < 4; ++dt) {
      ushort4 o;
      o.x = f2bf_bits(Oa[dt][0] * inv);
      o.y = f2bf_bits(Oa[dt][1] * inv);
      o.z = f2bf_bits(Oa[dt][2] * inv);
      o.w = f2bf_bits(Oa[dt][3] * inv);
      *reinterpret_cast<ushort4*>(att + (size_t)myq * C_DIM + h * 64 + dt * 16 + hi * 4) = o;
    }
  } else {
    // partial store: Opart[slot][q_local 64][d 64] f32 (un-divided), lpart[slot][q_local]
    const int slot = ((qb64 - 32) * 12 + h) * 2 + half;
    float* Ob = Opart + (((size_t)slot * 64) + wv * 16 + llo) * 64;
    #pragma unroll
    for (int dt = 0; dt < 4; ++dt)
      *reinterpret_cast<f32x4*>(Ob + dt * 16 + hi * 4) = Oa[dt];
    if (hi == 0) lpart[slot * 64 + wv * 16 + llo] = l;
  }
}

// Merge the 2 kv-halves for qb64 32..63: att = (O0+O1)/(l0+l1).
__global__ __launch_bounds__(256) void merge9(
    const float* __restrict__ Opart, const float* __restrict__ lpart,
    __bf16* __restrict__ att) {
  const int b = blockIdx.x;            // 0..383 = (qb64-32)*12 + h
  const int qi = b / 12, h = b - qi * 12;
  const int t = threadIdx.x;
  const int r = t >> 2, d0 = (t & 3) * 16;
  const int slot0 = b * 2;
  const float* O0 = Opart + ((size_t)slot0 * 64 + r) * 64 + d0;
  const float* O1 = Opart + ((size_t)(slot0 + 1) * 64 + r) * 64 + d0;
  const float linv = 1.f / (lpart[slot0 * 64 + r] + lpart[(slot0 + 1) * 64 + r]);
  __bf16* dst = att + ((size_t)(qi + 32) * 64 + r) * C_DIM + h * 64 + d0;
  #pragma unroll
  for (int i = 0; i < 4; ++i) {
    f32x4 a = *reinterpret_cast<const f32x4*>(O0 + i * 4);
    f32x4 c = *reinterpret_cast<const f32x4*>(O1 + i * 4);
    ushort4 o;
    o.x = f2bf_bits((a[0] + c[0]) * linv);
    o.y = f2bf_bits((a[1] + c[1]) * linv);
    o.z = f2bf_bits((a[2] + c[2]) * linv);
    o.w = f2bf_bits((a[3] + c[3]) * linv);
    *reinterpret_cast<ushort4*>(dst + i * 4) = o;
  }
}

extern "C" void kernel_launch(void* const* d_in, const int* in_sizes, int n_in,
                              void* d_out, int out_size, void* d_ws, size_t ws_size,
                              hipStream_t stream) {
  const float* x  = (const float*)d_in[0];
  const float* Wq = (const float*)d_in[1];
  const float* Wk = (const float*)d_in[2];
  const float* Wv = (const float*)d_in[3];
  const float* Wo = (const float*)d_in[4];
  const float* bo = (const float*)d_in[5];

  __bf16* xb   = (__bf16*)d_ws;                          // [4096][768]
  __bf16* Wqkv = xb + (size_t)S_TOT * C_DIM;             // [2304][768]
  __bf16* Wob  = Wqkv + (size_t)3 * C_DIM * C_DIM;       // [768][768]
  __bf16* QKV  = Wob + (size_t)C_DIM * C_DIM;            // [4096][2304] (V region unused)
  __bf16* Vtp  = QKV + (size_t)S_TOT * QKV_LD;           // [12][64][4096], pi-permuted
  __bf16* att  = Vtp + (size_t)NH * 64 * S_TOT;          // [4096][768]
  float*  Opart = (float*)(att + (size_t)S_TOT * C_DIM); // [768][64][64] f32
  float*  lpart = Opart + (size_t)768 * 64 * 64;         // [768][64] f32

  // fused cast of all five f32 inputs (x, Wq*QSCALE, Wk, Wv, Wo)
  {
    const int tot = S_TOT * C_DIM + 4 * C_DIM * C_DIM;   // 5,505,024
    cvt_all<<<dim3((tot / 4 + 255) / 256), dim3(256), 0, stream>>>(
        x, Wq, Wk, Wv, Wo, xb);
  }

  // QKV projection (128^2 tiles, fenced counted-vmcnt dbuf); V -> Vtp
  gemm128<false, true><<<dim3(QKV_LD / 128, S_TOT / 128), dim3(256), 0, stream>>>(
      xb, Wqkv, (void*)QKV, nullptr, Vtp, C_DIM, QKV_LD);

  // flash attention (kv-split) -> att rows 0..2047 direct + partials
  attn_fused9<<<dim3(1152), dim3(256), 0, stream>>>(QKV, Vtp, att, Opart, lpart);

  // merge kv-halves -> att rows 2048..4095
  merge9<<<dim3(384), dim3(256), 0, stream>>>(Opart, lpart, att);

  // out = att @ Wo^T + bo : f32
  gemm128<true, false><<<dim3(C_DIM / 128, S_TOT / 128), dim3(256), 0, stream>>>(
      att, Wob, d_out, bo, nullptr, C_DIM, C_DIM);
}

// Round 18
// 101.059 us; speedup vs baseline: 1.1038x; 1.1038x over previous
//
#include <hip/hip_runtime.h>

#define S_TOT 4096
#define C_DIM 768
#define QKV_LD 2304
#define NH 12
// 1/sqrt(64) * log2(e), folded into Wq so softmax runs in exp2 domain
#define QSCALE 0.18033688011112042f

using f32x4  = __attribute__((ext_vector_type(4))) float;
using bf16x8 = __attribute__((ext_vector_type(8))) __bf16;

#if __has_builtin(__builtin_amdgcn_exp2f)
#define EXP2(x) __builtin_amdgcn_exp2f(x)
#else
#define EXP2(x) exp2f(x)
#endif

// Full drain + barrier (GEMM single-buffer publish; replay race seen in R5
// when relying on implicit drain).
#define DRAIN_AND_BARRIER()                                     \
  do {                                                          \
    asm volatile("s_waitcnt vmcnt(0) lgkmcnt(0)" ::: "memory"); \
    __builtin_amdgcn_sched_barrier(0);                          \
    __syncthreads();                                            \
  } while (0)

__device__ inline unsigned short f2bf_bits(float f) {
  unsigned int u = __float_as_uint(f);
  u = (u + 0x7FFFu + ((u >> 16) & 1u)) >> 16;
  return (unsigned short)u;
}
__device__ inline __bf16 f2bf(float f) {
  unsigned short s = f2bf_bits(f);
  __bf16 b;
  __builtin_memcpy(&b, &s, 2);
  return b;
}

// async global->LDS, 16B per lane; LDS dest = wave-uniform base + lane*16
__device__ __forceinline__ void gl_lds16(const __bf16* g, __bf16* l) {
  __builtin_amdgcn_global_load_lds(
      (__attribute__((address_space(1))) void*)(g),
      (__attribute__((address_space(3))) void*)(l), 16, 0, 0);
}

// One fused f32->bf16 cast for x, Wq(scaled), Wk, Wv, Wo into contiguous ws.
__global__ void cvt_all(const float* __restrict__ x, const float* __restrict__ Wq,
                        const float* __restrict__ Wk, const float* __restrict__ Wv,
                        const float* __restrict__ Wo, __bf16* __restrict__ dst) {
  const int XN = S_TOT * C_DIM;      // 3145728
  const int WN = C_DIM * C_DIM;      // 589824
  int i = (blockIdx.x * blockDim.x + threadIdx.x) * 4;
  if (i >= XN + 4 * WN) return;
  const float* src; float scale = 1.f; int off;
  if (i < XN)               { src = x;  off = i; }
  else if (i < XN + WN)     { src = Wq; off = i - XN; scale = QSCALE; }
  else if (i < XN + 2 * WN) { src = Wk; off = i - XN - WN; }
  else if (i < XN + 3 * WN) { src = Wv; off = i - XN - 2 * WN; }
  else                      { src = Wo; off = i - XN - 3 * WN; }
  float4 v = *reinterpret_cast<const float4*>(src + off);
  ushort4 o;
  o.x = f2bf_bits(v.x * scale); o.y = f2bf_bits(v.y * scale);
  o.z = f2bf_bits(v.z * scale); o.w = f2bf_bits(v.w * scale);
  *reinterpret_cast<ushort4*>(reinterpret_cast<unsigned short*>(dst) + i) = o;
}

// C = A @ B^T, 128x128 tile, BK=64, 4 waves (2x2, each 64x64 = 4x4 frags).
// global_load_lds 16B staging, single-buffer 2-barrier K-loop, 16B-chunk XOR
// swizzle (compiler schedules the interior freely; R17 showed fenced dbuf is
// ~10us slower — m141 lesson). SPLIT_V: n-tiles >=1536 (V projection) written
// straight from registers into Vtp[h][d][tile64*64 + pi(local)] (v9 layout).
template<bool OUT_BIAS_F32, bool SPLIT_V>
__global__ __launch_bounds__(256) void gemm128(
    const __bf16* __restrict__ A, const __bf16* __restrict__ B,
    void* __restrict__ Cv, const float* __restrict__ bias,
    __bf16* __restrict__ VtOut, int K, int ldc) {
  __shared__ __bf16 As[128][64];
  __shared__ __bf16 Bs[128][64];
  const int t = threadIdx.x, lane = t & 63, wv = t >> 6;
  const int wr = wv >> 1, wc = wv & 1;
  const int lhi = lane >> 4, llo = lane & 15;
  const int m0 = blockIdx.y * 128, n0 = blockIdx.x * 128;

  f32x4 acc[4][4];
  #pragma unroll
  for (int a = 0; a < 4; ++a)
    #pragma unroll
    for (int b = 0; b < 4; ++b) acc[a][b] = (f32x4){0.f, 0.f, 0.f, 0.f};

  for (int kt = 0; kt < K; kt += 64) {
    __syncthreads();                       // previous tile fully consumed
    #pragma unroll
    for (int n = 0; n < 4; ++n) {
      const int ci = n * 256 + wv * 64 + lane;   // 16B-chunk id 0..1023
      const int r = ci >> 3;                     // tile row 0..127
      const int cc = (ci & 7) ^ (r & 7);         // inverse-swizzled src chunk
      gl_lds16(A + (size_t)(m0 + r) * K + kt + cc * 8, &As[0][0] + ci * 8);
      gl_lds16(B + (size_t)(n0 + r) * K + kt + cc * 8, &Bs[0][0] + ci * 8);
    }
    DRAIN_AND_BARRIER();
    #pragma unroll
    for (int kk = 0; kk < 2; ++kk) {
      bf16x8 af[4], bfr[4];
      #pragma unroll
      for (int mi = 0; mi < 4; ++mi) {
        const int row = wr * 64 + mi * 16 + llo;
        af[mi] = *reinterpret_cast<const bf16x8*>(
            &As[0][0] + row * 64 + (((kk << 2) | lhi) ^ (llo & 7)) * 8);
      }
      #pragma unroll
      for (int ni = 0; ni < 4; ++ni) {
        const int row = wc * 64 + ni * 16 + llo;
        bfr[ni] = *reinterpret_cast<const bf16x8*>(
            &Bs[0][0] + row * 64 + (((kk << 2) | lhi) ^ (llo & 7)) * 8);
      }
      #pragma unroll
      for (int mi = 0; mi < 4; ++mi)
        #pragma unroll
        for (int ni = 0; ni < 4; ++ni)
          acc[mi][ni] = __builtin_amdgcn_mfma_f32_16x16x32_bf16(af[mi], bfr[ni], acc[mi][ni], 0, 0, 0);
    }
  }

  if (SPLIT_V && n0 >= 1536) {
    // V projection: write registers straight to pi-permuted Vtp (v9 layout).
    const int head = (n0 - 1536 + wc * 64) >> 6;       // uniform per wave
    const int tile64 = (m0 >> 6) + wr;
    #pragma unroll
    for (int mi = 0; mi < 4; ++mi) {
      const int p = (mi >> 1) * 32 + lhi * 8 + (mi & 1) * 4;
      #pragma unroll
      for (int ni = 0; ni < 4; ++ni) {
        const int d = ni * 16 + llo;
        ushort4 o;
        o.x = f2bf_bits(acc[mi][ni][0]); o.y = f2bf_bits(acc[mi][ni][1]);
        o.z = f2bf_bits(acc[mi][ni][2]); o.w = f2bf_bits(acc[mi][ni][3]);
        uint2 u; __builtin_memcpy(&u, &o, 8);
        *reinterpret_cast<uint2*>(VtOut + ((size_t)head * 64 + d) * S_TOT + tile64 * 64 + p) = u;
      }
    }
    return;
  }

  #pragma unroll
  for (int mi = 0; mi < 4; ++mi)
    #pragma unroll
    for (int ni = 0; ni < 4; ++ni)
      #pragma unroll
      for (int i = 0; i < 4; ++i) {
        const int row = m0 + wr * 64 + mi * 16 + lhi * 4 + i;
        const int col = n0 + wc * 64 + ni * 16 + llo;
        if constexpr (OUT_BIAS_F32) {
          reinterpret_cast<float*>(Cv)[(size_t)row * ldc + col] = acc[mi][ni][i] + bias[col];
        } else {
          reinterpret_cast<__bf16*>(Cv)[(size_t)row * ldc + col] = f2bf(acc[mi][ni][i]);
        }
      }
}

// v9 block decode: 1152 blocks, heavy-first weight classes. Views 4-7
// (qb64 32..63) are split 2-ways over kv (additive O/l partials, merged by
// merge9); views 0-3 unsplit. Bijective over the 1152 units.
__device__ __forceinline__ void decode9(int j, int& qb64, int& h, int& half, bool& split) {
  if (j < 192)      { split = true;  half = j & 1;  qb64 = 56 + ((j >> 1) & 7); h = j >> 4; }
  else if (j < 288) { int k = j - 192; split = false; half = 0; qb64 = 24 + (k & 7); h = k >> 3; }
  else if (j < 480) { int k = j - 288; split = true;  half = k & 1; qb64 = 48 + ((k >> 1) & 7); h = k >> 4; }
  else if (j < 672) { int k = j - 480; split = true;  half = k & 1; qb64 = 40 + ((k >> 1) & 7); h = k >> 4; }
  else if (j < 768) { int k = j - 672; split = false; half = 0; qb64 = 16 + (k & 7); h = k >> 3; }
  else if (j < 960) { int k = j - 768; split = true;  half = k & 1; qb64 = 32 + ((k >> 1) & 7); h = k >> 4; }
  else              { int k = j - 960; split = false; half = 0; qb64 = k & 15; h = k >> 4; }
}

// Flash attention v9 (best measured: 57.0 us attn, clean replay in R10):
// 4 waves / 64 q-rows per block; kv-split per decode9. K AND V staged in
// triple-buffered LDS, depth-2 counted-vmcnt pipeline (steady vmcnt(4),
// never 0 mid-loop), raw s_barrier. Max-free exp2 softmax (O, l additive
// over kv). Split blocks store f32 partials for merge9.
__global__ __launch_bounds__(256) void attn_fused9(
    const __bf16* __restrict__ QKV, const __bf16* __restrict__ Vtp,
    __bf16* __restrict__ att, float* __restrict__ Opart,
    float* __restrict__ lpart) {
  __shared__ __bf16 Ks[3][64][64];
  __shared__ __bf16 Vs[3][64][64];
  const int t = threadIdx.x, lane = t & 63, wv = t >> 6;
  const int llo = lane & 15, hi = lane >> 4;
  const int sw = llo & 7;
  int qb64, h, half; bool split;
  decode9((int)blockIdx.x, qb64, h, half, split);
  const int vq = qb64 >> 3;
  const int kv_end = (vq <= 1) ? 1024 : (vq + 1) * 512;
  const int n_tiles = split ? (kv_end >> 7) : (kv_end >> 6);   // 16..32
  const int kstart = split ? half * (kv_end >> 1) : 0;
  const int q0 = qb64 * 64;
  const int myq = q0 + wv * 16 + llo;

  bf16x8 qf[2];
  {
    const __bf16* qrow = QKV + (size_t)myq * QKV_LD + h * 64;
    qf[0] = *reinterpret_cast<const bf16x8*>(qrow + hi * 8);
    qf[1] = *reinterpret_cast<const bf16x8*>(qrow + 32 + hi * 8);
  }
  // Drain q loads so the only in-loop vmem stream is the counted gl_lds set.
  asm volatile("s_waitcnt vmcnt(0)" ::: "memory");

  f32x4 Oa[4];
  #pragma unroll
  for (int dt = 0; dt < 4; ++dt) Oa[dt] = (f32x4){0.f, 0.f, 0.f, 0.f};
  float l = 0.f;   // per-lane partial (own 16 keys per tile); reduced at end

  // Per-thread staging pointers: two 16B chunks each of K and V per tile,
  // advanced by fixed strides (stages are issued in tile order).
  const int ci0 = (wv * 2 + 0) * 64 + lane, r0 = ci0 >> 3, c0 = (ci0 & 7) ^ (r0 & 7);
  const int ci1 = (wv * 2 + 1) * 64 + lane, r1 = ci1 >> 3, c1 = (ci1 & 7) ^ (r1 & 7);
  const __bf16* kp0 = QKV + (size_t)(kstart + r0) * QKV_LD + C_DIM + h * 64 + c0 * 8;
  const __bf16* kp1 = QKV + (size_t)(kstart + r1) * QKV_LD + C_DIM + h * 64 + c1 * 8;
  const __bf16* vp0 = Vtp + ((size_t)h * 64 + r0) * S_TOT + kstart + c0 * 8;
  const __bf16* vp1 = Vtp + ((size_t)h * 64 + r1) * S_TOT + kstart + c1 * 8;
  __bf16* const kd0 = &Ks[0][0][0] + (wv * 2 + 0) * 512;   // wave-uniform base
  __bf16* const kd1 = &Ks[0][0][0] + (wv * 2 + 1) * 512;
  __bf16* const vd0 = &Vs[0][0][0] + (wv * 2 + 0) * 512;
  __bf16* const vd1 = &Vs[0][0][0] + (wv * 2 + 1) * 512;

  auto stage = [&](int buf) {
    const size_t bo = (size_t)buf * 4096;
    gl_lds16(kp0, kd0 + bo);
    gl_lds16(vp0, vd0 + bo);
    gl_lds16(kp1, kd1 + bo);
    gl_lds16(vp1, vd1 + bo);
    kp0 += (size_t)64 * QKV_LD; kp1 += (size_t)64 * QKV_LD;
    vp0 += 64; vp1 += 64;
  };

  stage(0);
  stage(1);
  int cur = 0;
  for (int tt = 0; tt < n_tiles; ++tt) {
    // retire tile tt's 4 loads; keep tile tt+1's 4 in flight (when present)
    if (tt + 1 < n_tiles) {
      asm volatile("s_waitcnt vmcnt(4)" ::: "memory");
    } else {
      asm volatile("s_waitcnt vmcnt(0)" ::: "memory");
    }
    __builtin_amdgcn_sched_barrier(0);
    __builtin_amdgcn_s_barrier();
    __builtin_amdgcn_sched_barrier(0);
    if (tt + 2 < n_tiles) {
      const int nxt = (cur + 2 >= 3) ? cur - 1 : cur + 2;
      stage(nxt);
    }
    const __bf16* Kb = &Ks[cur][0][0];
    const __bf16* Vb = &Vs[cur][0][0];

    // ---- QK^T (swapped): 8 mfma, operands from swizzled LDS
    f32x4 sc[4];
    #pragma unroll
    for (int nt = 0; nt < 4; ++nt) sc[nt] = (f32x4){0.f, 0.f, 0.f, 0.f};
    #pragma unroll
    for (int nt = 0; nt < 4; ++nt) {
      const __bf16* kr = Kb + (nt * 16 + llo) * 64;
      bf16x8 kf0 = *reinterpret_cast<const bf16x8*>(kr + ((hi ^ sw) * 8));
      bf16x8 kf1 = *reinterpret_cast<const bf16x8*>(kr + (((4 + hi) ^ sw) * 8));
      sc[nt] = __builtin_amdgcn_mfma_f32_16x16x32_bf16(kf0, qf[0], sc[nt], 0, 0, 0);
      sc[nt] = __builtin_amdgcn_mfma_f32_16x16x32_bf16(kf1, qf[1], sc[nt], 0, 0, 0);
    }

    // ---- P = exp2(S) directly (no max; scores' std ~1.44, f32 catastrophe
    // needs S > 115), per-lane l partial
    float pp[4][4];
    #pragma unroll
    for (int nt = 0; nt < 4; ++nt)
      #pragma unroll
      for (int i = 0; i < 4; ++i) pp[nt][i] = EXP2(sc[nt][i]);
    float t0 = (pp[0][0] + pp[0][1]) + (pp[0][2] + pp[0][3]);
    float t1 = (pp[1][0] + pp[1][1]) + (pp[1][2] + pp[1][3]);
    float t2 = (pp[2][0] + pp[2][1]) + (pp[2][2] + pp[2][3]);
    float t3 = (pp[3][0] + pp[3][1]) + (pp[3][2] + pp[3][3]);
    l += (t0 + t1) + (t2 + t3);

    bf16x8 pf[2];
    #pragma unroll
    for (int mm = 0; mm < 2; ++mm)
      #pragma unroll
      for (int jj = 0; jj < 8; ++jj)
        pf[mm][jj] = (__bf16)pp[2 * mm + (jj >> 2)][jj & 3];

    // ---- PV (swapped, O^T): 8 mfma
    #pragma unroll
    for (int dt = 0; dt < 4; ++dt) {
      const __bf16* vr = Vb + (dt * 16 + llo) * 64;
      #pragma unroll
      for (int mm = 0; mm < 2; ++mm) {
        bf16x8 va = *reinterpret_cast<const bf16x8*>(vr + (((mm * 4 + hi) ^ sw) * 8));
        Oa[dt] = __builtin_amdgcn_mfma_f32_16x16x32_bf16(va, pf[mm], Oa[dt], 0, 0, 0);
      }
    }
    cur = (cur + 1 == 3) ? 0 : cur + 1;
  }

  // ---- epilogue
  l += __shfl_xor(l, 16);
  l += __shfl_xor(l, 32);
  if (!split) {
    const float inv = 1.f / l;
    #pragma unroll
    for (int dt = 0; dt < 4; ++dt) {
      ushort4 o;
      o.x = f2bf_bits(Oa[dt][0] * inv);
      o.y = f2bf_bits(Oa[dt][1] * inv);
      o.z = f2bf_bits(Oa[dt][2] * inv);
      o.w = f2bf_bits(Oa[dt][3] * inv);
      *reinterpret_cast<ushort4*>(att + (size_t)myq * C_DIM + h * 64 + dt * 16 + hi * 4) = o;
    }
  } else {
    // partial store: Opart[slot][q_local 64][d 64] f32 (un-divided), lpart[slot][q_local]
    const int slot = ((qb64 - 32) * 12 + h) * 2 + half;
    float* Ob = Opart + (((size_t)slot * 64) + wv * 16 + llo) * 64;
    #pragma unroll
    for (int dt = 0; dt < 4; ++dt)
      *reinterpret_cast<f32x4*>(Ob + dt * 16 + hi * 4) = Oa[dt];
    if (hi == 0) lpart[slot * 64 + wv * 16 + llo] = l;
  }
}

// Merge the 2 kv-halves for qb64 32..63: att = (O0+O1)/(l0+l1).
__global__ __launch_bounds__(256) void merge9(
    const float* __restrict__ Opart, const float* __restrict__ lpart,
    __bf16* __restrict__ att) {
  const int b = blockIdx.x;            // 0..383 = (qb64-32)*12 + h
  const int qi = b / 12, h = b - qi * 12;
  const int t = threadIdx.x;
  const int r = t >> 2, d0 = (t & 3) * 16;
  const int slot0 = b * 2;
  const float* O0 = Opart + ((size_t)slot0 * 64 + r) * 64 + d0;
  const float* O1 = Opart + ((size_t)(slot0 + 1) * 64 + r) * 64 + d0;
  const float linv = 1.f / (lpart[slot0 * 64 + r] + lpart[(slot0 + 1) * 64 + r]);
  __bf16* dst = att + ((size_t)(qi + 32) * 64 + r) * C_DIM + h * 64 + d0;
  #pragma unroll
  for (int i = 0; i < 4; ++i) {
    f32x4 a = *reinterpret_cast<const f32x4*>(O0 + i * 4);
    f32x4 c = *reinterpret_cast<const f32x4*>(O1 + i * 4);
    ushort4 o;
    o.x = f2bf_bits((a[0] + c[0]) * linv);
    o.y = f2bf_bits((a[1] + c[1]) * linv);
    o.z = f2bf_bits((a[2] + c[2]) * linv);
    o.w = f2bf_bits((a[3] + c[3]) * linv);
    *reinterpret_cast<ushort4*>(dst + i * 4) = o;
  }
}

extern "C" void kernel_launch(void* const* d_in, const int* in_sizes, int n_in,
                              void* d_out, int out_size, void* d_ws, size_t ws_size,
                              hipStream_t stream) {
  const float* x  = (const float*)d_in[0];
  const float* Wq = (const float*)d_in[1];
  const float* Wk = (const float*)d_in[2];
  const float* Wv = (const float*)d_in[3];
  const float* Wo = (const float*)d_in[4];
  const float* bo = (const float*)d_in[5];

  __bf16* xb   = (__bf16*)d_ws;                          // [4096][768]
  __bf16* Wqkv = xb + (size_t)S_TOT * C_DIM;             // [2304][768]
  __bf16* Wob  = Wqkv + (size_t)3 * C_DIM * C_DIM;       // [768][768]
  __bf16* QKV  = Wob + (size_t)C_DIM * C_DIM;            // [4096][2304] (V region unused)
  __bf16* Vtp  = QKV + (size_t)S_TOT * QKV_LD;           // [12][64][4096], pi-permuted
  __bf16* att  = Vtp + (size_t)NH * 64 * S_TOT;          // [4096][768]
  float*  Opart = (float*)(att + (size_t)S_TOT * C_DIM); // [768][64][64] f32
  float*  lpart = Opart + (size_t)768 * 64 * 64;         // [768][64] f32

  // fused cast of all five f32 inputs (x, Wq*QSCALE, Wk, Wv, Wo)
  {
    const int tot = S_TOT * C_DIM + 4 * C_DIM * C_DIM;   // 5,505,024
    cvt_all<<<dim3((tot / 4 + 255) / 256), dim3(256), 0, stream>>>(
        x, Wq, Wk, Wv, Wo, xb);
  }

  // QKV projection (128^2 tiles); V -> Vtp (pi-permuted)
  gemm128<false, true><<<dim3(QKV_LD / 128, S_TOT / 128), dim3(256), 0, stream>>>(
      xb, Wqkv, (void*)QKV, nullptr, Vtp, C_DIM, QKV_LD);

  // flash attention (kv-split) -> att rows 0..2047 direct + partials
  attn_fused9<<<dim3(1152), dim3(256), 0, stream>>>(QKV, Vtp, att, Opart, lpart);

  // merge kv-halves -> att rows 2048..4095
  merge9<<<dim3(384), dim3(256), 0, stream>>>(Opart, lpart, att);

  // out = att @ Wo^T + bo : f32
  gemm128<true, false><<<dim3(C_DIM / 128, S_TOT / 128), dim3(256), 0, stream>>>(
      att, Wob, d_out, bo, nullptr, C_DIM, C_DIM);
}